// Round 1
// baseline (8121.632 us; speedup 1.0000x reference)
//
#include <hip/hip_runtime.h>
#include <cstdint>
#include <cstddef>

// ---------------- problem constants ----------------
#define B_   16
#define L_   1022
#define E_   1280
#define D_   512
#define H_   8
#define FF_  2048
#define NL_  4
#define DH_  64
#define BL_  (B_*L_)      // 16352
#define EPS_ 1e-5f

// ======================================================================
// RoPE cos/sin tables: cos[l*64+d], d in [0,64), freq index j = d & 31
// ======================================================================
__global__ void tables_k(float* __restrict__ ct, float* __restrict__ st) {
    int idx = blockIdx.x * blockDim.x + threadIdx.x;
    if (idx >= L_ * DH_) return;
    int l = idx / DH_;
    int d = idx % DH_;
    int j = d & 31;
    float invf = powf(10000.0f, -(float)(2 * j) / (float)DH_);
    float ang = (float)l * invf;
    ct[idx] = cosf(ang);
    st[idx] = sinf(ang);
}

// ======================================================================
// Tiled fp32 GEMM: C[M,N] = act(A[M,K] @ W[N,K]^T + bias) (+resid)
// BM=BN=128, BK=16, 256 threads, 8x8 micro-tile.
// ROWBIAS: bias points to gpart[B][N], indexed by (m / L_).
// ======================================================================
template<bool RELU, bool RESID, bool ROWBIAS>
__global__ __launch_bounds__(256)
void gemm_k(const float* __restrict__ A, const float* __restrict__ W,
            const float* __restrict__ bias, const float* __restrict__ resid,
            float* __restrict__ C, int M, int N, int K, int ldw)
{
    __shared__ float As[16][128];
    __shared__ float Ws[16][128];
    const int nt = N >> 7;
    const int bx = blockIdx.x % nt;
    const int by = blockIdx.x / nt;
    const int m0 = by << 7, n0 = bx << 7;
    const int tid = threadIdx.x;
    const int tx = tid & 15, ty = tid >> 4;

    float acc[8][8];
#pragma unroll
    for (int i = 0; i < 8; i++)
#pragma unroll
        for (int j = 0; j < 8; j++) acc[i][j] = 0.0f;

    for (int k0 = 0; k0 < K; k0 += 16) {
#pragma unroll
        for (int u = 0; u < 2; u++) {
            int f = tid + (u << 8);
            int row = f >> 2;
            int c4 = (f & 3) << 2;
            int m = m0 + row;
            float4 av = make_float4(0.f, 0.f, 0.f, 0.f);
            if (m < M) av = *(const float4*)(A + (size_t)m * K + k0 + c4);
            As[c4 + 0][row] = av.x; As[c4 + 1][row] = av.y;
            As[c4 + 2][row] = av.z; As[c4 + 3][row] = av.w;
            float4 wv = *(const float4*)(W + (size_t)(n0 + row) * ldw + k0 + c4);
            Ws[c4 + 0][row] = wv.x; Ws[c4 + 1][row] = wv.y;
            Ws[c4 + 2][row] = wv.z; Ws[c4 + 3][row] = wv.w;
        }
        __syncthreads();
#pragma unroll
        for (int k = 0; k < 16; k++) {
            float a[8], b[8];
            *(float4*)(a)     = *(const float4*)(&As[k][ty * 8]);
            *(float4*)(a + 4) = *(const float4*)(&As[k][ty * 8 + 4]);
            *(float4*)(b)     = *(const float4*)(&Ws[k][tx * 8]);
            *(float4*)(b + 4) = *(const float4*)(&Ws[k][tx * 8 + 4]);
#pragma unroll
            for (int i = 0; i < 8; i++)
#pragma unroll
                for (int j = 0; j < 8; j++)
                    acc[i][j] = fmaf(a[i], b[j], acc[i][j]);
        }
        __syncthreads();
    }

    float bv[8];
    if constexpr (!ROWBIAS) {
#pragma unroll
        for (int j = 0; j < 8; j++) bv[j] = bias[n0 + tx * 8 + j];
    }
#pragma unroll
    for (int i = 0; i < 8; i++) {
        int m = m0 + ty * 8 + i;
        if (m >= M) continue;
        float ov[8];
        const float* rb = nullptr;
        if constexpr (ROWBIAS) rb = bias + (size_t)(m / L_) * N;
#pragma unroll
        for (int j = 0; j < 8; j++) {
            float c = acc[i][j];
            if constexpr (ROWBIAS) c += rb[n0 + tx * 8 + j];
            else                   c += bv[j];
            if constexpr (RELU) c = fmaxf(c, 0.0f);
            if constexpr (RESID) c += resid[(size_t)m * N + n0 + tx * 8 + j];
            ov[j] = c;
        }
        *(float4*)(C + (size_t)m * N + n0 + tx * 8)     = *(float4*)(ov);
        *(float4*)(C + (size_t)m * N + n0 + tx * 8 + 4) = *(float4*)(ov + 4);
    }
}

// ======================================================================
// LayerNorm: one wave per row; DD = 512 or 128; optional fused ReLU.
// ======================================================================
template<int DD, bool RELU>
__global__ __launch_bounds__(256)
void ln_k(const float* __restrict__ x, const float* __restrict__ s,
          const float* __restrict__ bb, float* __restrict__ out, int M)
{
    const int lane = threadIdx.x & 63;
    const int row = (blockIdx.x << 2) + (threadIdx.x >> 6);
    if (row >= M) return;
    const float* xr = x + (size_t)row * DD;
    constexpr int NV = DD / 64;
    float v[NV];
    if constexpr (NV == 8) {
        *(float4*)(v)     = *(const float4*)(xr + lane * 8);
        *(float4*)(v + 4) = *(const float4*)(xr + lane * 8 + 4);
    } else {
        float2 t = *(const float2*)(xr + lane * 2);
        v[0] = t.x; v[1] = t.y;
    }
    float sum = 0.f, sq = 0.f;
#pragma unroll
    for (int e = 0; e < NV; e++) { sum += v[e]; sq += v[e] * v[e]; }
#pragma unroll
    for (int msk = 1; msk < 64; msk <<= 1) {
        sum += __shfl_xor(sum, msk);
        sq  += __shfl_xor(sq, msk);
    }
    const float mean = sum * (1.0f / DD);
    const float var  = sq * (1.0f / DD) - mean * mean;
    const float rstd = rsqrtf(var + EPS_);
    float* orow = out + (size_t)row * DD;
#pragma unroll
    for (int e = 0; e < NV; e++) {
        int d = lane * NV + e;
        float r = (v[e] - mean) * rstd * s[d] + bb[d];
        if constexpr (RELU) r = fmaxf(r, 0.0f);
        v[e] = r;
    }
    if constexpr (NV == 8) {
        *(float4*)(orow + lane * 8)     = *(float4*)(v);
        *(float4*)(orow + lane * 8 + 4) = *(float4*)(v + 4);
    } else {
        float2 t; t.x = v[0]; t.y = v[1];
        *(float2*)(orow + lane * 2) = t;
    }
}

// ======================================================================
// RoPE applied to n[BL,512] (per 64-dim head) -> r
// ======================================================================
__global__ __launch_bounds__(256)
void rope_k(const float* __restrict__ n, const float* __restrict__ ct,
            const float* __restrict__ st, float* __restrict__ r)
{
    int idx4 = blockIdx.x * blockDim.x + threadIdx.x;
    if (idx4 >= BL_ * D_ / 4) return;
    int idx = idx4 << 2;
    int l = (idx / D_) % L_;
    int d = idx & (D_ - 1);
    int dd = d & 63;
    float4 xv = *(const float4*)(n + idx);
    float4 c  = *(const float4*)(ct + l * DH_ + dd);
    float4 sv = *(const float4*)(st + l * DH_ + dd);
    float4 pv; float sgn;
    if (dd < 32) { pv = *(const float4*)(n + idx + 32); sgn = -1.0f; }
    else         { pv = *(const float4*)(n + idx - 32); sgn =  1.0f; }
    float4 o;
    o.x = xv.x * c.x + sgn * pv.x * sv.x;
    o.y = xv.y * c.y + sgn * pv.y * sv.y;
    o.z = xv.z * c.z + sgn * pv.z * sv.z;
    o.w = xv.w * c.w + sgn * pv.w * sv.w;
    *(float4*)(r + idx) = o;
}

// ======================================================================
// Flash attention: block = (b, h, 64-query tile); K/V tiles of 64 in LDS.
// q,k,v,o layouts: [B*L, 512] with head offset h*64.
// ======================================================================
__global__ __launch_bounds__(256)
void attn_k(const float* __restrict__ q, const float* __restrict__ kk_,
            const float* __restrict__ v, const float* __restrict__ mask,
            float* __restrict__ o)
{
    const int QT = 16;
    const int bh = blockIdx.x / QT, qt = blockIdx.x % QT;
    const int b = bh >> 3, h = bh & 7;
    __shared__ float QsT[64][64];   // [d][q], pre-scaled by 1/8
    __shared__ float KP[64][64];    // K^T [d][k], then P^T [k][q]
    __shared__ float Vs[64][64];    // [k][d]
    const int tid = threadIdx.x;
    const int tx = tid & 15, ty = tid >> 4;
    const size_t basebl = (size_t)b * L_;

#pragma unroll
    for (int u = 0; u < 4; u++) {
        int f = tid + (u << 8);
        int qi = f >> 4, d4 = (f & 15) << 2;
        int l = qt * 64 + qi;
        float4 qv = make_float4(0.f, 0.f, 0.f, 0.f);
        if (l < L_) qv = *(const float4*)(q + (basebl + l) * D_ + h * DH_ + d4);
        QsT[d4 + 0][qi] = qv.x * 0.125f; QsT[d4 + 1][qi] = qv.y * 0.125f;
        QsT[d4 + 2][qi] = qv.z * 0.125f; QsT[d4 + 3][qi] = qv.w * 0.125f;
    }

    float m_run[4], l_run[4], oacc[4][4];
#pragma unroll
    for (int i = 0; i < 4; i++) {
        m_run[i] = -1e30f; l_run[i] = 0.f;
#pragma unroll
        for (int j = 0; j < 4; j++) oacc[i][j] = 0.f;
    }

    for (int kt = 0; kt < 16; kt++) {
        __syncthreads();   // previous tile's PV reads done (also covers Q staging)
#pragma unroll
        for (int u = 0; u < 4; u++) {
            int f = tid + (u << 8);
            int ki = f >> 4, d4 = (f & 15) << 2;
            int lk = kt * 64 + ki;
            float4 kv = make_float4(0.f, 0.f, 0.f, 0.f);
            float4 vv = make_float4(0.f, 0.f, 0.f, 0.f);
            if (lk < L_) {
                kv = *(const float4*)(kk_ + (basebl + lk) * D_ + h * DH_ + d4);
                vv = *(const float4*)(v   + (basebl + lk) * D_ + h * DH_ + d4);
            }
            KP[d4 + 0][ki] = kv.x; KP[d4 + 1][ki] = kv.y;
            KP[d4 + 2][ki] = kv.z; KP[d4 + 3][ki] = kv.w;
            *(float4*)(&Vs[ki][d4]) = vv;
        }
        __syncthreads();

        // S = Q K^T, rows 4*ty+i (q), cols 4*tx+j (k)
        float s[4][4];
#pragma unroll
        for (int i = 0; i < 4; i++)
#pragma unroll
            for (int j = 0; j < 4; j++) s[i][j] = 0.f;
        for (int d = 0; d < 64; d++) {
            float4 a = *(const float4*)(&QsT[d][ty * 4]);
            float4 bb = *(const float4*)(&KP[d][tx * 4]);
            const float av[4] = {a.x, a.y, a.z, a.w};
            const float bv2[4] = {bb.x, bb.y, bb.z, bb.w};
#pragma unroll
            for (int i = 0; i < 4; i++)
#pragma unroll
                for (int j = 0; j < 4; j++)
                    s[i][j] = fmaf(av[i], bv2[j], s[i][j]);
        }
        // mask invalid keys
#pragma unroll
        for (int j = 0; j < 4; j++) {
            int lk = kt * 64 + tx * 4 + j;
            bool valid = (lk < L_) && (mask[basebl + lk] > 0.0f);
            if (!valid) { s[0][j] = -1e30f; s[1][j] = -1e30f; s[2][j] = -1e30f; s[3][j] = -1e30f; }
        }
        // online softmax (row groups = 16 contiguous lanes)
        float p[4][4];
#pragma unroll
        for (int i = 0; i < 4; i++) {
            float tm = fmaxf(fmaxf(s[i][0], s[i][1]), fmaxf(s[i][2], s[i][3]));
#pragma unroll
            for (int msk = 1; msk <= 8; msk <<= 1) tm = fmaxf(tm, __shfl_xor(tm, msk));
            float nm = fmaxf(m_run[i], tm);
            float corr = __expf(m_run[i] - nm);
            m_run[i] = nm;
            float ts = 0.f;
#pragma unroll
            for (int j = 0; j < 4; j++) { p[i][j] = __expf(s[i][j] - nm); ts += p[i][j]; }
#pragma unroll
            for (int msk = 1; msk <= 8; msk <<= 1) ts += __shfl_xor(ts, msk);
            l_run[i] = l_run[i] * corr + ts;
#pragma unroll
            for (int j = 0; j < 4; j++) oacc[i][j] *= corr;
        }
        __syncthreads();   // all K^T reads done before overwrite
        // write P^T [k][q]
#pragma unroll
        for (int i = 0; i < 4; i++)
#pragma unroll
            for (int j = 0; j < 4; j++)
                KP[tx * 4 + j][ty * 4 + i] = p[i][j];
        __syncthreads();
        // O += P V : rows q = 4*ty+i, cols d = 4*tx+j
        for (int kj = 0; kj < 64; kj++) {
            float4 a = *(const float4*)(&KP[kj][ty * 4]);
            float4 vv = *(const float4*)(&Vs[kj][tx * 4]);
            const float av[4] = {a.x, a.y, a.z, a.w};
            const float vv2[4] = {vv.x, vv.y, vv.z, vv.w};
#pragma unroll
            for (int i = 0; i < 4; i++)
#pragma unroll
                for (int j = 0; j < 4; j++)
                    oacc[i][j] = fmaf(av[i], vv2[j], oacc[i][j]);
        }
    }

#pragma unroll
    for (int i = 0; i < 4; i++) {
        int l = qt * 64 + ty * 4 + i;
        if (l >= L_) continue;
        float inv = 1.0f / l_run[i];
        float ov[4];
#pragma unroll
        for (int j = 0; j < 4; j++) ov[j] = oacc[i][j] * inv;
        *(float4*)(o + (basebl + l) * D_ + h * DH_ + tx * 4) = *(float4*)(ov);
    }
}

// ======================================================================
// masked mean pool over L : gctx[b][d]
// ======================================================================
__global__ __launch_bounds__(512)
void pool_k(const float* __restrict__ x, const float* __restrict__ mask,
            float* __restrict__ g)
{
    const int b = blockIdx.x;
    const int d = threadIdx.x;
    float acc = 0.f, ms = 0.f;
    for (int l = 0; l < L_; l++) {
        float mv = mask[b * L_ + l];
        acc += x[((size_t)b * L_ + l) * D_ + d] * mv;
        ms += mv;
    }
    g[b * D_ + d] = acc / ms;
}

// ======================================================================
// gpart[b][j] = h1_b[j] + sum_c gctx[b][c] * h1_w[j*1024 + 512 + c]
// one wave per (b,j)
// ======================================================================
__global__ __launch_bounds__(256)
void gpart_k(const float* __restrict__ g, const float* __restrict__ h1w,
             const float* __restrict__ h1b, float* __restrict__ gp)
{
    const int lane = threadIdx.x & 63;
    const int gid = (blockIdx.x << 2) + (threadIdx.x >> 6);
    const int b = gid >> 7, j = gid & 127;
    const float* wr = h1w + (size_t)j * (2 * D_) + D_;
    const float* gr = g + b * D_;
    float4 a0 = *(const float4*)(gr + lane * 8);
    float4 a1 = *(const float4*)(gr + lane * 8 + 4);
    float4 w0 = *(const float4*)(wr + lane * 8);
    float4 w1v = *(const float4*)(wr + lane * 8 + 4);
    float acc = a0.x * w0.x + a0.y * w0.y + a0.z * w0.z + a0.w * w0.w
              + a1.x * w1v.x + a1.y * w1v.y + a1.z * w1v.z + a1.w * w1v.w;
#pragma unroll
    for (int msk = 1; msk < 64; msk <<= 1) acc += __shfl_xor(acc, msk);
    if (lane == 0) gp[b * 128 + j] = acc + h1b[j];
}

// ======================================================================
// logits[m] = h2_b + dot(h[m, 0:128], h2_w)   (one wave per row)
// ======================================================================
__global__ __launch_bounds__(256)
void logits_k(const float* __restrict__ h, const float* __restrict__ w,
              const float* __restrict__ bsc, float* __restrict__ out, int M)
{
    const int lane = threadIdx.x & 63;
    const int row = (blockIdx.x << 2) + (threadIdx.x >> 6);
    if (row >= M) return;
    float2 hv = *(const float2*)(h + (size_t)row * 128 + lane * 2);
    float2 wv = *(const float2*)(w + lane * 2);
    float acc = hv.x * wv.x + hv.y * wv.y;
#pragma unroll
    for (int msk = 1; msk < 64; msk <<= 1) acc += __shfl_xor(acc, msk);
    if (lane == 0) out[row] = acc + bsc[0];
}

// ======================================================================
// host orchestration
// ======================================================================
extern "C" void kernel_launch(void* const* d_in, const int* in_sizes, int n_in,
                              void* d_out, int out_size, void* d_ws, size_t ws_size,
                              hipStream_t stream)
{
    const float* emb       = (const float*)d_in[0];
    const float* mask      = (const float*)d_in[1];
    // d_in[2] = position (unused)
    const float* proj_w    = (const float*)d_in[3];
    const float* proj_b    = (const float*)d_in[4];
    const float* proj_ln_s = (const float*)d_in[5];
    const float* proj_ln_b = (const float*)d_in[6];
    const float* ln1_s     = (const float*)d_in[7];
    const float* ln1_b     = (const float*)d_in[8];
    const float* in_w      = (const float*)d_in[9];
    const float* in_b      = (const float*)d_in[10];
    const float* out_w     = (const float*)d_in[11];
    const float* out_b     = (const float*)d_in[12];
    const float* ln2_s     = (const float*)d_in[13];
    const float* ln2_b     = (const float*)d_in[14];
    const float* w1        = (const float*)d_in[15];
    const float* b1        = (const float*)d_in[16];
    const float* w2        = (const float*)d_in[17];
    const float* b2        = (const float*)d_in[18];
    const float* h1_w      = (const float*)d_in[19];
    const float* h1_b      = (const float*)d_in[20];
    const float* hln_s     = (const float*)d_in[21];
    const float* hln_b     = (const float*)d_in[22];
    const float* h2_w      = (const float*)d_in[23];
    const float* h2_b      = (const float*)d_in[24];
    float* out = (float*)d_out;

    float* ws = (float*)d_ws;
    const size_t S = (size_t)BL_ * D_;
    float* X  = ws;             // persistent residual stream
    float* Nb = ws + S;         // LN output / head tmp
    float* Q  = ws + 2 * S;     // FF buffer = [Q, Kb, V, R] (4S)
    float* Kb = ws + 3 * S;
    float* V  = ws + 4 * S;
    float* R  = ws + 5 * S;     // rope out / attn out
    float* FFb = Q;
    float* CT = ws + 6 * S;
    float* ST = CT + L_ * DH_;
    float* GC = ST + L_ * DH_;
    float* GP = GC + B_ * D_;
    float* Hb = Nb;

    const int MT = (BL_ + 127) / 128;      // 128 M-tiles
    const dim3 blk(256);
    const int lnGrid = (BL_ + 3) / 4;

    tables_k<<<(L_ * DH_ + 255) / 256, blk, 0, stream>>>(CT, ST);

    // x = LN(emb @ proj_w.T + proj_b)
    gemm_k<false,false,false><<<MT * (D_ / 128), blk, 0, stream>>>(
        emb, proj_w, proj_b, nullptr, R, BL_, D_, E_, E_);
    ln_k<D_,false><<<lnGrid, blk, 0, stream>>>(R, proj_ln_s, proj_ln_b, X, BL_);

    for (int i = 0; i < NL_; i++) {
        const float* iw = in_w + (size_t)i * 3 * D_ * D_;
        const float* ib = in_b + (size_t)i * 3 * D_;
        ln_k<D_,false><<<lnGrid, blk, 0, stream>>>(X, ln1_s + i * D_, ln1_b + i * D_, Nb, BL_);
        // v = n @ wv.T
        gemm_k<false,false,false><<<MT * 4, blk, 0, stream>>>(
            Nb, iw + 2 * D_ * D_, ib + 2 * D_, nullptr, V, BL_, D_, D_, D_);
        // r = rope(n); q = r @ wq.T; k = r @ wk.T
        rope_k<<<(BL_ * D_ / 4 + 255) / 256, blk, 0, stream>>>(Nb, CT, ST, R);
        gemm_k<false,false,false><<<MT * 4, blk, 0, stream>>>(
            R, iw, ib, nullptr, Q, BL_, D_, D_, D_);
        gemm_k<false,false,false><<<MT * 4, blk, 0, stream>>>(
            R, iw + D_ * D_, ib + D_, nullptr, Kb, BL_, D_, D_, D_);
        // attention -> R
        attn_k<<<B_ * H_ * 16, blk, 0, stream>>>(Q, Kb, V, mask, R);
        // x = x + o @ out_w.T + out_b
        gemm_k<false,true,false><<<MT * 4, blk, 0, stream>>>(
            R, out_w + (size_t)i * D_ * D_, out_b + i * D_, X, X, BL_, D_, D_, D_);
        // FF block
        ln_k<D_,false><<<lnGrid, blk, 0, stream>>>(X, ln2_s + i * D_, ln2_b + i * D_, Nb, BL_);
        gemm_k<true,false,false><<<MT * 16, blk, 0, stream>>>(
            Nb, w1 + (size_t)i * FF_ * D_, b1 + i * FF_, nullptr, FFb, BL_, FF_, D_, D_);
        gemm_k<false,true,false><<<MT * 4, blk, 0, stream>>>(
            FFb, w2 + (size_t)i * D_ * FF_, b2 + i * D_, X, X, BL_, D_, FF_, FF_);
    }

    // head
    pool_k<<<B_, dim3(512), 0, stream>>>(X, mask, GC);
    gpart_k<<<(B_ * 128) / 4, blk, 0, stream>>>(GC, h1_w, h1_b, GP);
    gemm_k<false,false,true><<<MT * 1, blk, 0, stream>>>(
        X, h1_w, GP, nullptr, Hb, BL_, 128, D_, 2 * D_);
    ln_k<128,true><<<lnGrid, blk, 0, stream>>>(Hb, hln_s, hln_b, Hb, BL_);
    logits_k<<<lnGrid, blk, 0, stream>>>(Hb, h2_w, h2_b, out, BL_);
}

// Round 4
// 3163.116 us; speedup vs baseline: 2.5676x; 2.5676x over previous
//
#include <hip/hip_runtime.h>
#include <cstdint>
#include <cstddef>

// ---------------- problem constants ----------------
#define B_   16
#define L_   1022
#define E_   1280
#define D_   512
#define H_   8
#define FF_  2048
#define NL_  4
#define DH_  64
#define BL_  (B_*L_)      // 16352
#define EPS_ 1e-5f

typedef unsigned short u16;
typedef unsigned int   u32;
typedef float f32x4 __attribute__((ext_vector_type(4)));
typedef short s16x8 __attribute__((ext_vector_type(8)));

__device__ __forceinline__ u16 f2bf(float f) {
    u32 u = __builtin_bit_cast(u32, f);
    u += 0x7fffu + ((u >> 16) & 1u);
    return (u16)(u >> 16);
}
__device__ __forceinline__ float bf2f(u16 u) {
    return __builtin_bit_cast(float, (u32)u << 16);
}

// ======================================================================
// fp32 -> bf16 cast, 8 elems/thread
// ======================================================================
__global__ __launch_bounds__(256)
void cast_k(const float* __restrict__ src, u16* __restrict__ dst, int n8) {
    int t = blockIdx.x * 256 + threadIdx.x;
    if (t >= n8) return;
    const float* s = src + (size_t)t * 8;
    float4 a = *(const float4*)(s);
    float4 b = *(const float4*)(s + 4);
    s16x8 o;
    o[0] = (short)f2bf(a.x); o[1] = (short)f2bf(a.y);
    o[2] = (short)f2bf(a.z); o[3] = (short)f2bf(a.w);
    o[4] = (short)f2bf(b.x); o[5] = (short)f2bf(b.y);
    o[6] = (short)f2bf(b.z); o[7] = (short)f2bf(b.w);
    *(s16x8*)(dst + (size_t)t * 8) = o;
}

// h1_w left half [128, 0:512] (row stride 1024) -> packed bf16 [128,512]
__global__ __launch_bounds__(256)
void h1cast_k(const float* __restrict__ src, u16* __restrict__ dst) {
    int t = blockIdx.x * 256 + threadIdx.x;
    if (t >= 128 * 512 / 8) return;
    int row = t >> 6, c8 = (t & 63) << 3;
    const float* s = src + (size_t)row * 1024 + c8;
    float4 a = *(const float4*)(s);
    float4 b = *(const float4*)(s + 4);
    s16x8 o;
    o[0] = (short)f2bf(a.x); o[1] = (short)f2bf(a.y);
    o[2] = (short)f2bf(a.z); o[3] = (short)f2bf(a.w);
    o[4] = (short)f2bf(b.x); o[5] = (short)f2bf(b.y);
    o[6] = (short)f2bf(b.z); o[7] = (short)f2bf(b.w);
    *(s16x8*)(dst + (size_t)row * 512 + c8) = o;
}

// ======================================================================
// RoPE cos/sin tables
// ======================================================================
__global__ void tables_k(float* __restrict__ ct, float* __restrict__ st) {
    int idx = blockIdx.x * blockDim.x + threadIdx.x;
    if (idx >= L_ * DH_) return;
    int l = idx / DH_;
    int d = idx % DH_;
    int j = d & 31;
    float invf = powf(10000.0f, -(float)(2 * j) / (float)DH_);
    float ang = (float)l * invf;
    ct[idx] = cosf(ang);
    st[idx] = sinf(ang);
}

// ======================================================================
// bf16 MFMA GEMM: C[M,N] = act(A[M,K] @ W[N,K]^T + bias) (+resid)
// 128x128 tile, BK=64, 256 threads (4 waves, 2x2), 4x4 16x16 frags/wave.
// Register-staged LDS (global dwordx4 -> ds_write_b128), padded LDS rows.
// A,W bf16; C fp32 or bf16 (OUTBF). ROWBIAS: bias = gpart[B][N] by row/L.
// ======================================================================
template<bool RELU, bool RESID, bool OUTBF, bool ROWBIAS>
__global__ __launch_bounds__(256)
void mgemm_k(const u16* __restrict__ A, const u16* __restrict__ W,
             const float* __restrict__ bias, const float* __restrict__ resid,
             void* __restrict__ Cout, int M, int N, int K)
{
    constexpr int LDT = 72;               // padded LDS row stride (bf16), 144B
    __shared__ u16 As[128 * LDT];
    __shared__ u16 Ws[128 * LDT];
    const int nt = N >> 7;
    const int bx = blockIdx.x % nt;
    const int by = blockIdx.x / nt;
    const int m0 = by << 7, n0 = bx << 7;
    const int tid = threadIdx.x;
    const int lane = tid & 63, wid = tid >> 6;
    const int wr = wid >> 1, wc = wid & 1;
    const int lr = lane & 15, lk = lane >> 4;

    f32x4 acc[4][4];
#pragma unroll
    for (int m = 0; m < 4; m++)
#pragma unroll
        for (int n = 0; n < 4; n++) acc[m][n] = (f32x4)0.0f;

    for (int k0 = 0; k0 < K; k0 += 64) {
        // load 8 x 16B chunks (4 for A-tile, 4 for W-tile) to registers
        s16x8 va[4], vw[4];
#pragma unroll
        for (int u = 0; u < 4; u++) {
            int ch = tid + (u << 8);          // 16B chunk id, 0..1023
            int r = ch >> 3, c8 = (ch & 7) << 3;
            int ar = m0 + r; if (ar >= M) ar = M - 1;
            va[u] = *(const s16x8*)(A + (size_t)ar * K + k0 + c8);
            vw[u] = *(const s16x8*)(W + (size_t)(n0 + r) * K + k0 + c8);
        }
        __syncthreads();   // previous iteration's LDS reads complete
#pragma unroll
        for (int u = 0; u < 4; u++) {
            int ch = tid + (u << 8);
            int r = ch >> 3, c8 = (ch & 7) << 3;
            *(s16x8*)&As[r * LDT + c8] = va[u];
            *(s16x8*)&Ws[r * LDT + c8] = vw[u];
        }
        __syncthreads();   // tiles staged
#pragma unroll
        for (int kk = 0; kk < 2; kk++) {
            s16x8 af[4], bf[4];
#pragma unroll
            for (int m = 0; m < 4; m++)
                af[m] = *(const s16x8*)&As[(wr * 64 + m * 16 + lr) * LDT + kk * 32 + lk * 8];
#pragma unroll
            for (int n = 0; n < 4; n++)
                bf[n] = *(const s16x8*)&Ws[(wc * 64 + n * 16 + lr) * LDT + kk * 32 + lk * 8];
#pragma unroll
            for (int m = 0; m < 4; m++)
#pragma unroll
                for (int n = 0; n < 4; n++)
                    acc[m][n] = __builtin_amdgcn_mfma_f32_16x16x32_bf16(
                        af[m], bf[n], acc[m][n], 0, 0, 0);
        }
    }

    float bv[4];
    if constexpr (!ROWBIAS) {
#pragma unroll
        for (int n = 0; n < 4; n++) bv[n] = bias[n0 + wc * 64 + n * 16 + lr];
    }
#pragma unroll
    for (int m = 0; m < 4; m++) {
#pragma unroll
        for (int j = 0; j < 4; j++) {
            int row = m0 + wr * 64 + m * 16 + lk * 4 + j;
            if (row >= M) continue;
            const float* rb = nullptr;
            if constexpr (ROWBIAS) rb = bias + (size_t)(row / L_) * N;
#pragma unroll
            for (int n = 0; n < 4; n++) {
                int col = n0 + wc * 64 + n * 16 + lr;
                float c = acc[m][n][j];
                if constexpr (ROWBIAS) c += rb[col];
                else                   c += bv[n];
                if constexpr (RELU) c = fmaxf(c, 0.0f);
                if constexpr (RESID) c += resid[(size_t)row * N + col];
                if constexpr (OUTBF) ((u16*)Cout)[(size_t)row * N + col] = f2bf(c);
                else                 ((float*)Cout)[(size_t)row * N + col] = c;
            }
        }
    }
}

// ======================================================================
// LayerNorm: one wave per row; optional ReLU; optional bf16 output.
// ======================================================================
template<int DD, bool RELU, bool OUTBF>
__global__ __launch_bounds__(256)
void ln_k(const float* __restrict__ x, const float* __restrict__ s,
          const float* __restrict__ bb, void* __restrict__ out, int M)
{
    const int lane = threadIdx.x & 63;
    const int row = (blockIdx.x << 2) + (threadIdx.x >> 6);
    if (row >= M) return;
    const float* xr = x + (size_t)row * DD;
    constexpr int NV = DD / 64;
    float v[NV];
    if constexpr (NV == 8) {
        *(float4*)(v)     = *(const float4*)(xr + lane * 8);
        *(float4*)(v + 4) = *(const float4*)(xr + lane * 8 + 4);
    } else {
        float2 t = *(const float2*)(xr + lane * 2);
        v[0] = t.x; v[1] = t.y;
    }
    float sum = 0.f, sq = 0.f;
#pragma unroll
    for (int e = 0; e < NV; e++) { sum += v[e]; sq += v[e] * v[e]; }
#pragma unroll
    for (int msk = 1; msk < 64; msk <<= 1) {
        sum += __shfl_xor(sum, msk);
        sq  += __shfl_xor(sq, msk);
    }
    const float mean = sum * (1.0f / DD);
    const float var  = sq * (1.0f / DD) - mean * mean;
    const float rstd = rsqrtf(var + EPS_);
#pragma unroll
    for (int e = 0; e < NV; e++) {
        int d = lane * NV + e;
        float r = (v[e] - mean) * rstd * s[d] + bb[d];
        if constexpr (RELU) r = fmaxf(r, 0.0f);
        v[e] = r;
    }
    if constexpr (OUTBF) {
        u16* orow = (u16*)out + (size_t)row * DD;
        if constexpr (NV == 8) {
            s16x8 o;
#pragma unroll
            for (int e = 0; e < 8; e++) o[e] = (short)f2bf(v[e]);
            *(s16x8*)(orow + lane * 8) = o;
        } else {
            orow[lane * 2] = f2bf(v[0]); orow[lane * 2 + 1] = f2bf(v[1]);
        }
    } else {
        float* orow = (float*)out + (size_t)row * DD;
        if constexpr (NV == 8) {
            *(float4*)(orow + lane * 8)     = *(float4*)(v);
            *(float4*)(orow + lane * 8 + 4) = *(float4*)(v + 4);
        } else {
            float2 t; t.x = v[0]; t.y = v[1];
            *(float2*)(orow + lane * 2) = t;
        }
    }
}

// ======================================================================
// RoPE on bf16 [BL,512] -> bf16, 8 elems/thread
// ======================================================================
__global__ __launch_bounds__(256)
void rope_k(const u16* __restrict__ n, const float* __restrict__ ct,
            const float* __restrict__ st, u16* __restrict__ r)
{
    int t = blockIdx.x * 256 + threadIdx.x;
    if (t >= BL_ * D_ / 8) return;
    int idx = t << 3;
    int l = (idx / D_) % L_;
    int d = idx & (D_ - 1);
    int dd = d & 63;
    s16x8 xv = *(const s16x8*)(n + idx);
    int pidx; float sgn;
    if (dd < 32) { pidx = idx + 32; sgn = -1.0f; }
    else         { pidx = idx - 32; sgn =  1.0f; }
    s16x8 pv = *(const s16x8*)(n + pidx);
    float4 c0 = *(const float4*)(ct + l * DH_ + dd);
    float4 c1 = *(const float4*)(ct + l * DH_ + dd + 4);
    float4 s0 = *(const float4*)(st + l * DH_ + dd);
    float4 s1 = *(const float4*)(st + l * DH_ + dd + 4);
    float cc[8] = {c0.x,c0.y,c0.z,c0.w,c1.x,c1.y,c1.z,c1.w};
    float ss[8] = {s0.x,s0.y,s0.z,s0.w,s1.x,s1.y,s1.z,s1.w};
    s16x8 o;
#pragma unroll
    for (int e = 0; e < 8; e++) {
        float xf = bf2f((u16)xv[e]);
        float pf = bf2f((u16)pv[e]);
        o[e] = (short)f2bf(xf * cc[e] + sgn * pf * ss[e]);
    }
    *(s16x8*)(r + idx) = o;
}

// ======================================================================
// Flash attention (fp32 math, bf16 in/out): block=(b,h,64-query tile)
// ======================================================================
__global__ __launch_bounds__(256)
void attn_k(const u16* __restrict__ q, const u16* __restrict__ kk_,
            const u16* __restrict__ v, const float* __restrict__ mask,
            u16* __restrict__ o)
{
    const int QT = 16;
    const int bh = blockIdx.x / QT, qt = blockIdx.x % QT;
    const int b = bh >> 3, h = bh & 7;
    __shared__ float QsT[64][64];   // [d][q], pre-scaled by 1/8
    __shared__ float KP[64][64];    // K^T [d][k], then P^T [k][q]
    __shared__ float Vs[64][64];    // [k][d]
    const int tid = threadIdx.x;
    const int tx = tid & 15, ty = tid >> 4;
    const size_t basebl = (size_t)b * L_;

#pragma unroll
    for (int u = 0; u < 2; u++) {
        int f = tid + (u << 8);
        int qi = f >> 3, d8 = (f & 7) << 3;
        int l = qt * 64 + qi;
        float fv[8] = {0,0,0,0,0,0,0,0};
        if (l < L_) {
            s16x8 x = *(const s16x8*)(q + (basebl + l) * D_ + h * DH_ + d8);
#pragma unroll
            for (int e = 0; e < 8; e++) fv[e] = bf2f((u16)x[e]);
        }
#pragma unroll
        for (int e = 0; e < 8; e++) QsT[d8 + e][qi] = fv[e] * 0.125f;
    }

    float m_run[4], l_run[4], oacc[4][4];
#pragma unroll
    for (int i = 0; i < 4; i++) {
        m_run[i] = -1e30f; l_run[i] = 0.f;
#pragma unroll
        for (int j = 0; j < 4; j++) oacc[i][j] = 0.f;
    }

    for (int kt = 0; kt < 16; kt++) {
        __syncthreads();
#pragma unroll
        for (int u = 0; u < 2; u++) {
            int f = tid + (u << 8);
            int ki = f >> 3, d8 = (f & 7) << 3;
            int lk = kt * 64 + ki;
            float kf[8] = {0,0,0,0,0,0,0,0};
            float vf[8] = {0,0,0,0,0,0,0,0};
            if (lk < L_) {
                s16x8 kx = *(const s16x8*)(kk_ + (basebl + lk) * D_ + h * DH_ + d8);
                s16x8 vx = *(const s16x8*)(v   + (basebl + lk) * D_ + h * DH_ + d8);
#pragma unroll
                for (int e = 0; e < 8; e++) { kf[e] = bf2f((u16)kx[e]); vf[e] = bf2f((u16)vx[e]); }
            }
#pragma unroll
            for (int e = 0; e < 8; e++) KP[d8 + e][ki] = kf[e];
            f32x4 v0 = {vf[0], vf[1], vf[2], vf[3]};
            f32x4 v1 = {vf[4], vf[5], vf[6], vf[7]};
            *(f32x4*)&Vs[ki][d8]     = v0;
            *(f32x4*)&Vs[ki][d8 + 4] = v1;
        }
        __syncthreads();

        float s[4][4];
#pragma unroll
        for (int i = 0; i < 4; i++)
#pragma unroll
            for (int j = 0; j < 4; j++) s[i][j] = 0.f;
        for (int d = 0; d < 64; d++) {
            float4 a = *(const float4*)(&QsT[d][ty * 4]);
            float4 bb = *(const float4*)(&KP[d][tx * 4]);
            const float av[4] = {a.x, a.y, a.z, a.w};
            const float bv2[4] = {bb.x, bb.y, bb.z, bb.w};
#pragma unroll
            for (int i = 0; i < 4; i++)
#pragma unroll
                for (int j = 0; j < 4; j++)
                    s[i][j] = fmaf(av[i], bv2[j], s[i][j]);
        }
#pragma unroll
        for (int j = 0; j < 4; j++) {
            int lk = kt * 64 + tx * 4 + j;
            bool valid = (lk < L_) && (mask[basebl + lk] > 0.0f);
            if (!valid) { s[0][j] = -1e30f; s[1][j] = -1e30f; s[2][j] = -1e30f; s[3][j] = -1e30f; }
        }
        float p[4][4];
#pragma unroll
        for (int i = 0; i < 4; i++) {
            float tm = fmaxf(fmaxf(s[i][0], s[i][1]), fmaxf(s[i][2], s[i][3]));
#pragma unroll
            for (int msk = 1; msk <= 8; msk <<= 1) tm = fmaxf(tm, __shfl_xor(tm, msk));
            float nm = fmaxf(m_run[i], tm);
            float corr = __expf(m_run[i] - nm);
            m_run[i] = nm;
            float ts = 0.f;
#pragma unroll
            for (int j = 0; j < 4; j++) { p[i][j] = __expf(s[i][j] - nm); ts += p[i][j]; }
#pragma unroll
            for (int msk = 1; msk <= 8; msk <<= 1) ts += __shfl_xor(ts, msk);
            l_run[i] = l_run[i] * corr + ts;
#pragma unroll
            for (int j = 0; j < 4; j++) oacc[i][j] *= corr;
        }
        __syncthreads();
#pragma unroll
        for (int i = 0; i < 4; i++)
#pragma unroll
            for (int j = 0; j < 4; j++)
                KP[tx * 4 + j][ty * 4 + i] = p[i][j];
        __syncthreads();
        for (int kj = 0; kj < 64; kj++) {
            float4 a = *(const float4*)(&KP[kj][ty * 4]);
            float4 vv = *(const float4*)(&Vs[kj][tx * 4]);
            const float av[4] = {a.x, a.y, a.z, a.w};
            const float vv2[4] = {vv.x, vv.y, vv.z, vv.w};
#pragma unroll
            for (int i = 0; i < 4; i++)
#pragma unroll
                for (int j = 0; j < 4; j++)
                    oacc[i][j] = fmaf(av[i], vv2[j], oacc[i][j]);
        }
    }

#pragma unroll
    for (int i = 0; i < 4; i++) {
        int l = qt * 64 + ty * 4 + i;
        if (l >= L_) continue;
        float inv = 1.0f / l_run[i];
#pragma unroll
        for (int j = 0; j < 4; j++)
            o[(basebl + l) * D_ + h * DH_ + tx * 4 + j] = f2bf(oacc[i][j] * inv);
    }
}

// ======================================================================
// masked mean pool over L
// ======================================================================
__global__ __launch_bounds__(512)
void pool_k(const float* __restrict__ x, const float* __restrict__ mask,
             float* __restrict__ g)
{
    const int b = blockIdx.x;
    const int d = threadIdx.x;
    float acc = 0.f, ms = 0.f;
    for (int l = 0; l < L_; l++) {
        float mv = mask[b * L_ + l];
        acc += x[((size_t)b * L_ + l) * D_ + d] * mv;
        ms += mv;
    }
    g[b * D_ + d] = acc / ms;
}

// ======================================================================
// gpart[b][j] = h1_b[j] + dot(gctx[b], h1_w[j, 512:1024])  (fp32)
// ======================================================================
__global__ __launch_bounds__(256)
void gpart_k(const float* __restrict__ g, const float* __restrict__ h1w,
             const float* __restrict__ h1b, float* __restrict__ gp)
{
    const int lane = threadIdx.x & 63;
    const int gid = (blockIdx.x << 2) + (threadIdx.x >> 6);
    const int b = gid >> 7, j = gid & 127;
    const float* wr = h1w + (size_t)j * (2 * D_) + D_;
    const float* gr = g + b * D_;
    float4 a0 = *(const float4*)(gr + lane * 8);
    float4 a1 = *(const float4*)(gr + lane * 8 + 4);
    float4 w0 = *(const float4*)(wr + lane * 8);
    float4 w1v = *(const float4*)(wr + lane * 8 + 4);
    float acc = a0.x * w0.x + a0.y * w0.y + a0.z * w0.z + a0.w * w0.w
              + a1.x * w1v.x + a1.y * w1v.y + a1.z * w1v.z + a1.w * w1v.w;
#pragma unroll
    for (int msk = 1; msk < 64; msk <<= 1) acc += __shfl_xor(acc, msk);
    if (lane == 0) gp[b * 128 + j] = acc + h1b[j];
}

// ======================================================================
// logits[m] = h2_b + dot(h[m,0:128], h2_w)
// ======================================================================
__global__ __launch_bounds__(256)
void logits_k(const float* __restrict__ h, const float* __restrict__ w,
              const float* __restrict__ bsc, float* __restrict__ out, int M)
{
    const int lane = threadIdx.x & 63;
    const int row = (blockIdx.x << 2) + (threadIdx.x >> 6);
    if (row >= M) return;
    float2 hv = *(const float2*)(h + (size_t)row * 128 + lane * 2);
    float2 wv = *(const float2*)(w + lane * 2);
    float acc = hv.x * wv.x + hv.y * wv.y;
#pragma unroll
    for (int msk = 1; msk < 64; msk <<= 1) acc += __shfl_xor(acc, msk);
    if (lane == 0) out[row] = acc + bsc[0];
}

// ======================================================================
// host orchestration
// ======================================================================
extern "C" void kernel_launch(void* const* d_in, const int* in_sizes, int n_in,
                              void* d_out, int out_size, void* d_ws, size_t ws_size,
                              hipStream_t stream)
{
    const float* emb       = (const float*)d_in[0];
    const float* mask      = (const float*)d_in[1];
    const float* proj_w    = (const float*)d_in[3];
    const float* proj_b    = (const float*)d_in[4];
    const float* proj_ln_s = (const float*)d_in[5];
    const float* proj_ln_b = (const float*)d_in[6];
    const float* ln1_s     = (const float*)d_in[7];
    const float* ln1_b     = (const float*)d_in[8];
    const float* in_w      = (const float*)d_in[9];
    const float* in_b      = (const float*)d_in[10];
    const float* out_w     = (const float*)d_in[11];
    const float* out_b     = (const float*)d_in[12];
    const float* ln2_s     = (const float*)d_in[13];
    const float* ln2_b     = (const float*)d_in[14];
    const float* w1        = (const float*)d_in[15];
    const float* b1        = (const float*)d_in[16];
    const float* w2        = (const float*)d_in[17];
    const float* b2        = (const float*)d_in[18];
    const float* h1_w      = (const float*)d_in[19];
    const float* h1_b      = (const float*)d_in[20];
    const float* hln_s     = (const float*)d_in[21];
    const float* hln_b     = (const float*)d_in[22];
    const float* h2_w      = (const float*)d_in[23];
    const float* h2_b      = (const float*)d_in[24];
    float* out = (float*)d_out;

    // ------------------------------------------------------------------
    // Workspace map (float offsets; S = BL*D = 8,372,224 floats).
    // ROUND-3 BUG FIX: FFb16 is BL*FF bf16 = 2S floats (was sized 1S and
    // overran into the weight region, corrupting in_w/out_w/w1 bf16 copies).
    //   [0,S)      X      fp32 residual stream
    //   [S,2S)     Rf     fp32 proj-out / head Hb; aliased by QB [S,1.5S),
    //                     KB [1.5S,2S) (time-disjoint: Rf dead after proj LN,
    //                     QB/KB dead before head)
    //   [2S,2.5S)  VB     bf16
    //   [2.5S,3S)  NbB    bf16 (LN out; X-cast at head)
    //   [3S,5S)    FFb16  bf16 2S; internally aliases (all time-disjoint):
    //                     embB  [3S,4.25S)  dead after proj GEMM
    //                     RopeB [3S,3.5S)   dead before FF1 writes
    //                     RB    [4S,4.5S)   dead before FF1 writes
    //   [5S,...)   bf16 weights (6,651,904 floats), then CT/ST/GC/GP
    // Total ~= 194.6 MB (< 201.5 MB proven in round 1).
    // ------------------------------------------------------------------
    float* ws = (float*)d_ws;
    const size_t S = (size_t)BL_ * D_;
    float* X  = ws;
    float* Rf = ws + S;
    u16* QB    = (u16*)(ws + S);
    u16* KB    = (u16*)(ws + S) + S;
    u16* VB    = (u16*)(ws + 2 * S);
    u16* NbB   = (u16*)(ws + 2 * S) + S;
    u16* FFb16 = (u16*)(ws + 3 * S);       // [3S,5S), 4S u16
    u16* RopeB = FFb16;                    // [3S,3.5S)
    u16* embB  = FFb16;                    // [3S,4.25S)
    u16* RB    = (u16*)(ws + 4 * S);       // [4S,4.5S)
    u16* projwB = (u16*)(ws + 5 * S);
    u16* iwB  = projwB + 512 * 1280;
    u16* owB  = iwB + (size_t)NL_ * 3 * D_ * D_;
    u16* w1B  = owB + (size_t)NL_ * D_ * D_;
    u16* w2B  = w1B + (size_t)NL_ * FF_ * D_;
    u16* h1wB = w2B + (size_t)NL_ * D_ * FF_;
    float* CT = ws + 5 * S + 6651904;      // 13,303,808 bf16 weights = 6,651,904 floats
    float* ST = CT + L_ * DH_;
    float* GC = ST + L_ * DH_;
    float* GP = GC + B_ * D_;
    float* Hb = Rf;

    const int MT = 128;                    // ceil(16352/128)
    const dim3 blk(256);
    const int lnGrid = (BL_ + 3) / 4;

    // weight + input casts
    cast_k<<<(BL_ * E_ / 8 + 255) / 256, blk, 0, stream>>>(emb, embB, BL_ * E_ / 8);
    cast_k<<<(512 * 1280 / 8 + 255) / 256, blk, 0, stream>>>(proj_w, projwB, 512 * 1280 / 8);
    cast_k<<<(NL_ * 3 * D_ * D_ / 8 + 255) / 256, blk, 0, stream>>>(in_w, iwB, NL_ * 3 * D_ * D_ / 8);
    cast_k<<<(NL_ * D_ * D_ / 8 + 255) / 256, blk, 0, stream>>>(out_w, owB, NL_ * D_ * D_ / 8);
    cast_k<<<(NL_ * FF_ * D_ / 8 + 255) / 256, blk, 0, stream>>>(w1, w1B, NL_ * FF_ * D_ / 8);
    cast_k<<<(NL_ * D_ * FF_ / 8 + 255) / 256, blk, 0, stream>>>(w2, w2B, NL_ * D_ * FF_ / 8);
    h1cast_k<<<(128 * 512 / 8 + 255) / 256, blk, 0, stream>>>(h1_w, h1wB);
    tables_k<<<(L_ * DH_ + 255) / 256, blk, 0, stream>>>(CT, ST);

    // x = LN(emb @ proj_w.T + proj_b)
    mgemm_k<false,false,false,false><<<MT * (D_ / 128), blk, 0, stream>>>(
        embB, projwB, proj_b, nullptr, Rf, BL_, D_, E_);
    ln_k<D_,false,false><<<lnGrid, blk, 0, stream>>>(Rf, proj_ln_s, proj_ln_b, X, BL_);

    for (int i = 0; i < NL_; i++) {
        const u16* iw = iwB + (size_t)i * 3 * D_ * D_;
        const float* ib = in_b + (size_t)i * 3 * D_;
        ln_k<D_,false,true><<<lnGrid, blk, 0, stream>>>(X, ln1_s + i * D_, ln1_b + i * D_, NbB, BL_);
        mgemm_k<false,false,true,false><<<MT * 4, blk, 0, stream>>>(
            NbB, iw + 2 * D_ * D_, ib + 2 * D_, nullptr, VB, BL_, D_, D_);
        rope_k<<<(BL_ * D_ / 8 + 255) / 256, blk, 0, stream>>>(NbB, CT, ST, RopeB);
        mgemm_k<false,false,true,false><<<MT * 4, blk, 0, stream>>>(
            RopeB, iw, ib, nullptr, QB, BL_, D_, D_);
        mgemm_k<false,false,true,false><<<MT * 4, blk, 0, stream>>>(
            RopeB, iw + D_ * D_, ib + D_, nullptr, KB, BL_, D_, D_);
        attn_k<<<B_ * H_ * 16, blk, 0, stream>>>(QB, KB, VB, mask, RB);
        mgemm_k<false,true,false,false><<<MT * 4, blk, 0, stream>>>(
            RB, owB + (size_t)i * D_ * D_, out_b + i * D_, X, X, BL_, D_, D_);
        ln_k<D_,false,true><<<lnGrid, blk, 0, stream>>>(X, ln2_s + i * D_, ln2_b + i * D_, NbB, BL_);
        mgemm_k<true,false,true,false><<<MT * 16, blk, 0, stream>>>(
            NbB, w1B + (size_t)i * FF_ * D_, b1 + i * FF_, nullptr, FFb16, BL_, FF_, D_);
        mgemm_k<false,true,false,false><<<MT * 4, blk, 0, stream>>>(
            FFb16, w2B + (size_t)i * D_ * FF_, b2 + i * D_, X, X, BL_, D_, FF_);
    }

    // head
    pool_k<<<B_, dim3(512), 0, stream>>>(X, mask, GC);
    gpart_k<<<(B_ * 128) / 4, blk, 0, stream>>>(GC, h1_w, h1_b, GP);
    cast_k<<<(int)((S / 8 + 255) / 256), blk, 0, stream>>>(X, NbB, (int)(S / 8));
    mgemm_k<false,false,false,true><<<MT * 1, blk, 0, stream>>>(
        NbB, h1wB, GP, nullptr, Hb, BL_, 128, D_);
    ln_k<128,true,false><<<lnGrid, blk, 0, stream>>>(Hb, hln_s, hln_b, Hb, BL_);
    logits_k<<<lnGrid, blk, 0, stream>>>(Hb, h2_w, h2_b, out, BL_);
}

// Round 5
// 1578.740 us; speedup vs baseline: 5.1444x; 2.0036x over previous
//
#include <hip/hip_runtime.h>
#include <cstdint>
#include <cstddef>

// ---------------- problem constants ----------------
#define B_   16
#define L_   1022
#define E_   1280
#define D_   512
#define H_   8
#define FF_  2048
#define NL_  4
#define DH_  64
#define BL_  (B_*L_)      // 16352
#define EPS_ 1e-5f

typedef unsigned short u16;
typedef unsigned int   u32;
typedef float f32x4 __attribute__((ext_vector_type(4)));
typedef short s16x8 __attribute__((ext_vector_type(8)));

__device__ __forceinline__ u16 f2bf(float f) {
    u32 u = __builtin_bit_cast(u32, f);
    u += 0x7fffu + ((u >> 16) & 1u);
    return (u16)(u >> 16);
}
__device__ __forceinline__ float bf2f(u16 u) {
    return __builtin_bit_cast(float, (u32)u << 16);
}

// ======================================================================
// fp32 -> bf16 cast, 8 elems/thread
// ======================================================================
__global__ __launch_bounds__(256)
void cast_k(const float* __restrict__ src, u16* __restrict__ dst, int n8) {
    int t = blockIdx.x * 256 + threadIdx.x;
    if (t >= n8) return;
    const float* s = src + (size_t)t * 8;
    float4 a = *(const float4*)(s);
    float4 b = *(const float4*)(s + 4);
    s16x8 o;
    o[0] = (short)f2bf(a.x); o[1] = (short)f2bf(a.y);
    o[2] = (short)f2bf(a.z); o[3] = (short)f2bf(a.w);
    o[4] = (short)f2bf(b.x); o[5] = (short)f2bf(b.y);
    o[6] = (short)f2bf(b.z); o[7] = (short)f2bf(b.w);
    *(s16x8*)(dst + (size_t)t * 8) = o;
}

// h1_w left half [128, 0:512] (row stride 1024) -> packed bf16 [128,512]
__global__ __launch_bounds__(256)
void h1cast_k(const float* __restrict__ src, u16* __restrict__ dst) {
    int t = blockIdx.x * 256 + threadIdx.x;
    if (t >= 128 * 512 / 8) return;
    int row = t >> 6, c8 = (t & 63) << 3;
    const float* s = src + (size_t)row * 1024 + c8;
    float4 a = *(const float4*)(s);
    float4 b = *(const float4*)(s + 4);
    s16x8 o;
    o[0] = (short)f2bf(a.x); o[1] = (short)f2bf(a.y);
    o[2] = (short)f2bf(a.z); o[3] = (short)f2bf(a.w);
    o[4] = (short)f2bf(b.x); o[5] = (short)f2bf(b.y);
    o[6] = (short)f2bf(b.z); o[7] = (short)f2bf(b.w);
    *(s16x8*)(dst + (size_t)row * 512 + c8) = o;
}

// ======================================================================
// RoPE cos/sin tables
// ======================================================================
__global__ void tables_k(float* __restrict__ ct, float* __restrict__ st) {
    int idx = blockIdx.x * blockDim.x + threadIdx.x;
    if (idx >= L_ * DH_) return;
    int l = idx / DH_;
    int d = idx % DH_;
    int j = d & 31;
    float invf = powf(10000.0f, -(float)(2 * j) / (float)DH_);
    float ang = (float)l * invf;
    ct[idx] = cosf(ang);
    st[idx] = sinf(ang);
}

// ======================================================================
// bf16 MFMA GEMM: C[M,N] = act(A[M,K] @ W[N,K]^T + bias) (+resid)
// 128x128 tile, BK=64, 256 threads (4 waves, 2x2), 4x4 16x16 frags/wave.
// ======================================================================
template<bool RELU, bool RESID, bool OUTBF, bool ROWBIAS>
__global__ __launch_bounds__(256)
void mgemm_k(const u16* __restrict__ A, const u16* __restrict__ W,
             const float* __restrict__ bias, const float* __restrict__ resid,
             void* __restrict__ Cout, int M, int N, int K)
{
    constexpr int LDT = 72;               // padded LDS row stride (bf16), 144B
    __shared__ u16 As[128 * LDT];
    __shared__ u16 Ws[128 * LDT];
    const int nt = N >> 7;
    const int bx = blockIdx.x % nt;
    const int by = blockIdx.x / nt;
    const int m0 = by << 7, n0 = bx << 7;
    const int tid = threadIdx.x;
    const int lane = tid & 63, wid = tid >> 6;
    const int wr = wid >> 1, wc = wid & 1;
    const int lr = lane & 15, lk = lane >> 4;

    f32x4 acc[4][4];
#pragma unroll
    for (int m = 0; m < 4; m++)
#pragma unroll
        for (int n = 0; n < 4; n++) acc[m][n] = (f32x4)0.0f;

    for (int k0 = 0; k0 < K; k0 += 64) {
        s16x8 va[4], vw[4];
#pragma unroll
        for (int u = 0; u < 4; u++) {
            int ch = tid + (u << 8);          // 16B chunk id, 0..1023
            int r = ch >> 3, c8 = (ch & 7) << 3;
            int ar = m0 + r; if (ar >= M) ar = M - 1;
            va[u] = *(const s16x8*)(A + (size_t)ar * K + k0 + c8);
            vw[u] = *(const s16x8*)(W + (size_t)(n0 + r) * K + k0 + c8);
        }
        __syncthreads();   // previous iteration's LDS reads complete
#pragma unroll
        for (int u = 0; u < 4; u++) {
            int ch = tid + (u << 8);
            int r = ch >> 3, c8 = (ch & 7) << 3;
            *(s16x8*)&As[r * LDT + c8] = va[u];
            *(s16x8*)&Ws[r * LDT + c8] = vw[u];
        }
        __syncthreads();   // tiles staged
#pragma unroll
        for (int kk = 0; kk < 2; kk++) {
            s16x8 af[4], bf[4];
#pragma unroll
            for (int m = 0; m < 4; m++)
                af[m] = *(const s16x8*)&As[(wr * 64 + m * 16 + lr) * LDT + kk * 32 + lk * 8];
#pragma unroll
            for (int n = 0; n < 4; n++)
                bf[n] = *(const s16x8*)&Ws[(wc * 64 + n * 16 + lr) * LDT + kk * 32 + lk * 8];
#pragma unroll
            for (int m = 0; m < 4; m++)
#pragma unroll
                for (int n = 0; n < 4; n++)
                    acc[m][n] = __builtin_amdgcn_mfma_f32_16x16x32_bf16(
                        af[m], bf[n], acc[m][n], 0, 0, 0);
        }
    }

    float bv[4];
    if constexpr (!ROWBIAS) {
#pragma unroll
        for (int n = 0; n < 4; n++) bv[n] = bias[n0 + wc * 64 + n * 16 + lr];
    }
#pragma unroll
    for (int m = 0; m < 4; m++) {
#pragma unroll
        for (int j = 0; j < 4; j++) {
            int row = m0 + wr * 64 + m * 16 + lk * 4 + j;
            if (row >= M) continue;
            const float* rb = nullptr;
            if constexpr (ROWBIAS) rb = bias + (size_t)(row / L_) * N;
#pragma unroll
            for (int n = 0; n < 4; n++) {
                int col = n0 + wc * 64 + n * 16 + lr;
                float c = acc[m][n][j];
                if constexpr (ROWBIAS) c += rb[col];
                else                   c += bv[n];
                if constexpr (RELU) c = fmaxf(c, 0.0f);
                if constexpr (RESID) c += resid[(size_t)row * N + col];
                if constexpr (OUTBF) ((u16*)Cout)[(size_t)row * N + col] = f2bf(c);
                else                 ((float*)Cout)[(size_t)row * N + col] = c;
            }
        }
    }
}

// ======================================================================
// LayerNorm: one wave per row; optional ReLU; optional bf16 output.
// ======================================================================
template<int DD, bool RELU, bool OUTBF>
__global__ __launch_bounds__(256)
void ln_k(const float* __restrict__ x, const float* __restrict__ s,
          const float* __restrict__ bb, void* __restrict__ out, int M)
{
    const int lane = threadIdx.x & 63;
    const int row = (blockIdx.x << 2) + (threadIdx.x >> 6);
    if (row >= M) return;
    const float* xr = x + (size_t)row * DD;
    constexpr int NV = DD / 64;
    float v[NV];
    if constexpr (NV == 8) {
        *(float4*)(v)     = *(const float4*)(xr + lane * 8);
        *(float4*)(v + 4) = *(const float4*)(xr + lane * 8 + 4);
    } else {
        float2 t = *(const float2*)(xr + lane * 2);
        v[0] = t.x; v[1] = t.y;
    }
    float sum = 0.f, sq = 0.f;
#pragma unroll
    for (int e = 0; e < NV; e++) { sum += v[e]; sq += v[e] * v[e]; }
#pragma unroll
    for (int msk = 1; msk < 64; msk <<= 1) {
        sum += __shfl_xor(sum, msk);
        sq  += __shfl_xor(sq, msk);
    }
    const float mean = sum * (1.0f / DD);
    const float var  = sq * (1.0f / DD) - mean * mean;
    const float rstd = rsqrtf(var + EPS_);
#pragma unroll
    for (int e = 0; e < NV; e++) {
        int d = lane * NV + e;
        float r = (v[e] - mean) * rstd * s[d] + bb[d];
        if constexpr (RELU) r = fmaxf(r, 0.0f);
        v[e] = r;
    }
    if constexpr (OUTBF) {
        u16* orow = (u16*)out + (size_t)row * DD;
        if constexpr (NV == 8) {
            s16x8 o;
#pragma unroll
            for (int e = 0; e < 8; e++) o[e] = (short)f2bf(v[e]);
            *(s16x8*)(orow + lane * 8) = o;
        } else {
            orow[lane * 2] = f2bf(v[0]); orow[lane * 2 + 1] = f2bf(v[1]);
        }
    } else {
        float* orow = (float*)out + (size_t)row * DD;
        if constexpr (NV == 8) {
            *(float4*)(orow + lane * 8)     = *(float4*)(v);
            *(float4*)(orow + lane * 8 + 4) = *(float4*)(v + 4);
        } else {
            float2 t; t.x = v[0]; t.y = v[1];
            *(float2*)(orow + lane * 2) = t;
        }
    }
}

// ======================================================================
// RoPE on bf16 [BL,512] -> bf16, 8 elems/thread
// ======================================================================
__global__ __launch_bounds__(256)
void rope_k(const u16* __restrict__ n, const float* __restrict__ ct,
            const float* __restrict__ st, u16* __restrict__ r)
{
    int t = blockIdx.x * 256 + threadIdx.x;
    if (t >= BL_ * D_ / 8) return;
    int idx = t << 3;
    int l = (idx / D_) % L_;
    int d = idx & (D_ - 1);
    int dd = d & 63;
    s16x8 xv = *(const s16x8*)(n + idx);
    int pidx; float sgn;
    if (dd < 32) { pidx = idx + 32; sgn = -1.0f; }
    else         { pidx = idx - 32; sgn =  1.0f; }
    s16x8 pv = *(const s16x8*)(n + pidx);
    float4 c0 = *(const float4*)(ct + l * DH_ + dd);
    float4 c1 = *(const float4*)(ct + l * DH_ + dd + 4);
    float4 s0 = *(const float4*)(st + l * DH_ + dd);
    float4 s1 = *(const float4*)(st + l * DH_ + dd + 4);
    float cc[8] = {c0.x,c0.y,c0.z,c0.w,c1.x,c1.y,c1.z,c1.w};
    float ss[8] = {s0.x,s0.y,s0.z,s0.w,s1.x,s1.y,s1.z,s1.w};
    s16x8 o;
#pragma unroll
    for (int e = 0; e < 8; e++) {
        float xf = bf2f((u16)xv[e]);
        float pf = bf2f((u16)pv[e]);
        o[e] = (short)f2bf(xf * cc[e] + sgn * pf * ss[e]);
    }
    *(s16x8*)(r + idx) = o;
}

// ======================================================================
// MFMA flash attention (bf16 in/out, fp32 softmax+accum)
// block = (b, h, 64-q-tile); 4 waves, wave w owns q-rows [w*16, w*16+16).
// Per 64-key tile: K in LDS [key][d], V^T in LDS [d][key], P bf16 in LDS
// [q][key] (wave-private rows). All LDS strides 68 u16 (conflict-free
// 16-row MFMA fragment reads: row stride 136B -> bank +2 per row).
// S-MFMA: A=Q(row=q,k=d), B=K^T(col=key,k=d); PV: A=P(row=q,k=key),
// B=V(col=d,k=key) via V^T tile. C layout: col=lane&15, row=4*(lane>>4)+j.
// ======================================================================
__global__ __launch_bounds__(256)
void attn_k(const u16* __restrict__ q, const u16* __restrict__ kk_,
            const u16* __restrict__ v, const float* __restrict__ mask,
            u16* __restrict__ o)
{
    constexpr int LDA = 68;   // u16 stride
    __shared__ u16 Kt[64 * LDA];
    __shared__ u16 Vt[64 * LDA];
    __shared__ u16 Pl[64 * LDA];
    const int bh = blockIdx.x >> 4, qt = blockIdx.x & 15;
    const int b = bh >> 3, h = bh & 7;
    const int tid = threadIdx.x;
    const int lane = tid & 63, w = tid >> 6;
    const int lr = lane & 15, lg = lane >> 4;
    const size_t basebl = (size_t)b * L_;

    // Q A-fragments (row = lr within wave's 16 rows; k = 32*kk + 8*lg + e)
    const int qrow = qt * 64 + w * 16 + lr;
    const int qclamp = qrow < L_ ? qrow : L_ - 1;
    s16x8 aq[2];
#pragma unroll
    for (int kk = 0; kk < 2; kk++)
        aq[kk] = *(const s16x8*)(q + (basebl + qclamp) * D_ + h * DH_ + kk * 32 + lg * 8);

    f32x4 oacc[4];
    float m_run[4], l_run[4];
#pragma unroll
    for (int n = 0; n < 4; n++) oacc[n] = (f32x4)0.0f;
#pragma unroll
    for (int j = 0; j < 4; j++) { m_run[j] = -1e30f; l_run[j] = 0.f; }

    for (int kt = 0; kt < 16; kt++) {
        __syncthreads();          // all waves done reading prev Kt/Vt
        // stage K [key][d] (vector) and V^T [d][key] (scalar transpose)
#pragma unroll
        for (int u = 0; u < 2; u++) {
            int ch = tid + (u << 8);
            int key = ch >> 3, d8 = (ch & 7) << 3;
            int gk = kt * 64 + key;
            int gkc = gk < L_ ? gk : L_ - 1;
            s16x8 kv = *(const s16x8*)(kk_ + (basebl + gkc) * D_ + h * DH_ + d8);
            s16x8 vv = *(const s16x8*)(v   + (basebl + gkc) * D_ + h * DH_ + d8);
            *(s16x8*)&Kt[key * LDA + d8] = kv;
#pragma unroll
            for (int e = 0; e < 8; e++) Vt[(d8 + e) * LDA + key] = (u16)vv[e];
        }
        __syncthreads();

        // S = Q K^T : col = key = n*16+lr, row = q = 4*lg+j
        f32x4 sacc[4];
#pragma unroll
        for (int n = 0; n < 4; n++) {
            sacc[n] = (f32x4)0.0f;
#pragma unroll
            for (int kk = 0; kk < 2; kk++) {
                s16x8 bk = *(const s16x8*)&Kt[(n * 16 + lr) * LDA + kk * 32 + lg * 8];
                sacc[n] = __builtin_amdgcn_mfma_f32_16x16x32_bf16(aq[kk], bk, sacc[n], 0, 0, 0);
            }
        }
        // key validity for this lane's columns
        bool val[4];
#pragma unroll
        for (int n = 0; n < 4; n++) {
            int key = kt * 64 + n * 16 + lr;
            val[n] = (key < L_) && (mask[basebl + key] > 0.0f);
        }
        // online softmax per j (row r = 4*lg + j; 16-lane group reduce)
#pragma unroll
        for (int j = 0; j < 4; j++) {
            float sv[4];
#pragma unroll
            for (int n = 0; n < 4; n++)
                sv[n] = val[n] ? sacc[n][j] * 0.125f : -1e30f;
            float tm = fmaxf(fmaxf(sv[0], sv[1]), fmaxf(sv[2], sv[3]));
#pragma unroll
            for (int msk = 1; msk <= 8; msk <<= 1) tm = fmaxf(tm, __shfl_xor(tm, msk));
            float nm = fmaxf(m_run[j], tm);
            float corr = __expf(m_run[j] - nm);
            m_run[j] = nm;
            float p[4], ts = 0.f;
#pragma unroll
            for (int n = 0; n < 4; n++) { p[n] = __expf(sv[n] - nm); ts += p[n]; }
#pragma unroll
            for (int msk = 1; msk <= 8; msk <<= 1) ts += __shfl_xor(ts, msk);
            l_run[j] = l_run[j] * corr + ts;
#pragma unroll
            for (int n = 0; n < 4; n++) {
                oacc[n][j] *= corr;
                Pl[(w * 16 + lg * 4 + j) * LDA + n * 16 + lr] = f2bf(p[n]);
            }
        }
        // PV: A = P (this wave's rows only -> intra-wave LDS dep, no barrier)
#pragma unroll
        for (int kk = 0; kk < 2; kk++) {
            s16x8 ap = *(const s16x8*)&Pl[(w * 16 + lr) * LDA + kk * 32 + lg * 8];
#pragma unroll
            for (int n = 0; n < 4; n++) {
                s16x8 bv = *(const s16x8*)&Vt[(n * 16 + lr) * LDA + kk * 32 + lg * 8];
                oacc[n] = __builtin_amdgcn_mfma_f32_16x16x32_bf16(ap, bv, oacc[n], 0, 0, 0);
            }
        }
    }

    // epilogue: rows q = qt*64 + w*16 + 4*lg + j, cols d = n*16 + lr
#pragma unroll
    for (int j = 0; j < 4; j++) {
        int qr = qt * 64 + w * 16 + lg * 4 + j;
        if (qr >= L_) continue;
        float inv = 1.0f / l_run[j];
#pragma unroll
        for (int n = 0; n < 4; n++)
            o[(basebl + qr) * D_ + h * DH_ + n * 16 + lr] = f2bf(oacc[n][j] * inv);
    }
}

// ======================================================================
// masked mean pool over L
// ======================================================================
__global__ __launch_bounds__(512)
void pool_k(const float* __restrict__ x, const float* __restrict__ mask,
             float* __restrict__ g)
{
    const int b = blockIdx.x;
    const int d = threadIdx.x;
    float acc = 0.f, ms = 0.f;
    for (int l = 0; l < L_; l++) {
        float mv = mask[b * L_ + l];
        acc += x[((size_t)b * L_ + l) * D_ + d] * mv;
        ms += mv;
    }
    g[b * D_ + d] = acc / ms;
}

// ======================================================================
// gpart[b][j] = h1_b[j] + dot(gctx[b], h1_w[j, 512:1024])  (fp32)
// ======================================================================
__global__ __launch_bounds__(256)
void gpart_k(const float* __restrict__ g, const float* __restrict__ h1w,
             const float* __restrict__ h1b, float* __restrict__ gp)
{
    const int lane = threadIdx.x & 63;
    const int gid = (blockIdx.x << 2) + (threadIdx.x >> 6);
    const int b = gid >> 7, j = gid & 127;
    const float* wr = h1w + (size_t)j * (2 * D_) + D_;
    const float* gr = g + b * D_;
    float4 a0 = *(const float4*)(gr + lane * 8);
    float4 a1 = *(const float4*)(gr + lane * 8 + 4);
    float4 w0 = *(const float4*)(wr + lane * 8);
    float4 w1v = *(const float4*)(wr + lane * 8 + 4);
    float acc = a0.x * w0.x + a0.y * w0.y + a0.z * w0.z + a0.w * w0.w
              + a1.x * w1v.x + a1.y * w1v.y + a1.z * w1v.z + a1.w * w1v.w;
#pragma unroll
    for (int msk = 1; msk < 64; msk <<= 1) acc += __shfl_xor(acc, msk);
    if (lane == 0) gp[b * 128 + j] = acc + h1b[j];
}

// ======================================================================
// logits[m] = h2_b + dot(h[m,0:128], h2_w)
// ======================================================================
__global__ __launch_bounds__(256)
void logits_k(const float* __restrict__ h, const float* __restrict__ w,
              const float* __restrict__ bsc, float* __restrict__ out, int M)
{
    const int lane = threadIdx.x & 63;
    const int row = (blockIdx.x << 2) + (threadIdx.x >> 6);
    if (row >= M) return;
    float2 hv = *(const float2*)(h + (size_t)row * 128 + lane * 2);
    float2 wv = *(const float2*)(w + lane * 2);
    float acc = hv.x * wv.x + hv.y * wv.y;
#pragma unroll
    for (int msk = 1; msk < 64; msk <<= 1) acc += __shfl_xor(acc, msk);
    if (lane == 0) out[row] = acc + bsc[0];
}

// ======================================================================
// host orchestration
// ======================================================================
extern "C" void kernel_launch(void* const* d_in, const int* in_sizes, int n_in,
                              void* d_out, int out_size, void* d_ws, size_t ws_size,
                              hipStream_t stream)
{
    const float* emb       = (const float*)d_in[0];
    const float* mask      = (const float*)d_in[1];
    const float* proj_w    = (const float*)d_in[3];
    const float* proj_b    = (const float*)d_in[4];
    const float* proj_ln_s = (const float*)d_in[5];
    const float* proj_ln_b = (const float*)d_in[6];
    const float* ln1_s     = (const float*)d_in[7];
    const float* ln1_b     = (const float*)d_in[8];
    const float* in_w      = (const float*)d_in[9];
    const float* in_b      = (const float*)d_in[10];
    const float* out_w     = (const float*)d_in[11];
    const float* out_b     = (const float*)d_in[12];
    const float* ln2_s     = (const float*)d_in[13];
    const float* ln2_b     = (const float*)d_in[14];
    const float* w1        = (const float*)d_in[15];
    const float* b1        = (const float*)d_in[16];
    const float* w2        = (const float*)d_in[17];
    const float* b2        = (const float*)d_in[18];
    const float* h1_w      = (const float*)d_in[19];
    const float* h1_b      = (const float*)d_in[20];
    const float* hln_s     = (const float*)d_in[21];
    const float* hln_b     = (const float*)d_in[22];
    const float* h2_w      = (const float*)d_in[23];
    const float* h2_b      = (const float*)d_in[24];
    float* out = (float*)d_out;

    // Workspace map (see round-3 notes): S = BL*D floats.
    float* ws = (float*)d_ws;
    const size_t S = (size_t)BL_ * D_;
    float* X  = ws;
    float* Rf = ws + S;
    u16* QB    = (u16*)(ws + S);
    u16* KB    = (u16*)(ws + S) + S;
    u16* VB    = (u16*)(ws + 2 * S);
    u16* NbB   = (u16*)(ws + 2 * S) + S;
    u16* FFb16 = (u16*)(ws + 3 * S);       // [3S,5S), 4S u16
    u16* RopeB = FFb16;                    // [3S,3.5S)
    u16* embB  = FFb16;                    // [3S,4.25S)
    u16* RB    = (u16*)(ws + 4 * S);       // [4S,4.5S)
    u16* projwB = (u16*)(ws + 5 * S);
    u16* iwB  = projwB + 512 * 1280;
    u16* owB  = iwB + (size_t)NL_ * 3 * D_ * D_;
    u16* w1B  = owB + (size_t)NL_ * D_ * D_;
    u16* w2B  = w1B + (size_t)NL_ * FF_ * D_;
    u16* h1wB = w2B + (size_t)NL_ * D_ * FF_;
    float* CT = ws + 5 * S + 6651904;
    float* ST = CT + L_ * DH_;
    float* GC = ST + L_ * DH_;
    float* GP = GC + B_ * D_;
    float* Hb = Rf;

    const int MT = 128;
    const dim3 blk(256);
    const int lnGrid = (BL_ + 3) / 4;

    cast_k<<<(BL_ * E_ / 8 + 255) / 256, blk, 0, stream>>>(emb, embB, BL_ * E_ / 8);
    cast_k<<<(512 * 1280 / 8 + 255) / 256, blk, 0, stream>>>(proj_w, projwB, 512 * 1280 / 8);
    cast_k<<<(NL_ * 3 * D_ * D_ / 8 + 255) / 256, blk, 0, stream>>>(in_w, iwB, NL_ * 3 * D_ * D_ / 8);
    cast_k<<<(NL_ * D_ * D_ / 8 + 255) / 256, blk, 0, stream>>>(out_w, owB, NL_ * D_ * D_ / 8);
    cast_k<<<(NL_ * FF_ * D_ / 8 + 255) / 256, blk, 0, stream>>>(w1, w1B, NL_ * FF_ * D_ / 8);
    cast_k<<<(NL_ * D_ * FF_ / 8 + 255) / 256, blk, 0, stream>>>(w2, w2B, NL_ * D_ * FF_ / 8);
    h1cast_k<<<(128 * 512 / 8 + 255) / 256, blk, 0, stream>>>(h1_w, h1wB);
    tables_k<<<(L_ * DH_ + 255) / 256, blk, 0, stream>>>(CT, ST);

    mgemm_k<false,false,false,false><<<MT * (D_ / 128), blk, 0, stream>>>(
        embB, projwB, proj_b, nullptr, Rf, BL_, D_, E_);
    ln_k<D_,false,false><<<lnGrid, blk, 0, stream>>>(Rf, proj_ln_s, proj_ln_b, X, BL_);

    for (int i = 0; i < NL_; i++) {
        const u16* iw = iwB + (size_t)i * 3 * D_ * D_;
        const float* ib = in_b + (size_t)i * 3 * D_;
        ln_k<D_,false,true><<<lnGrid, blk, 0, stream>>>(X, ln1_s + i * D_, ln1_b + i * D_, NbB, BL_);
        mgemm_k<false,false,true,false><<<MT * 4, blk, 0, stream>>>(
            NbB, iw + 2 * D_ * D_, ib + 2 * D_, nullptr, VB, BL_, D_, D_);
        rope_k<<<(BL_ * D_ / 8 + 255) / 256, blk, 0, stream>>>(NbB, CT, ST, RopeB);
        mgemm_k<false,false,true,false><<<MT * 4, blk, 0, stream>>>(
            RopeB, iw, ib, nullptr, QB, BL_, D_, D_);
        mgemm_k<false,false,true,false><<<MT * 4, blk, 0, stream>>>(
            RopeB, iw + D_ * D_, ib + D_, nullptr, KB, BL_, D_, D_);
        attn_k<<<B_ * H_ * 16, blk, 0, stream>>>(QB, KB, VB, mask, RB);
        mgemm_k<false,true,false,false><<<MT * 4, blk, 0, stream>>>(
            RB, owB + (size_t)i * D_ * D_, out_b + i * D_, X, X, BL_, D_, D_);
        ln_k<D_,false,true><<<lnGrid, blk, 0, stream>>>(X, ln2_s + i * D_, ln2_b + i * D_, NbB, BL_);
        mgemm_k<true,false,true,false><<<MT * 16, blk, 0, stream>>>(
            NbB, w1B + (size_t)i * FF_ * D_, b1 + i * FF_, nullptr, FFb16, BL_, FF_, D_);
        mgemm_k<false,true,false,false><<<MT * 4, blk, 0, stream>>>(
            FFb16, w2B + (size_t)i * D_ * FF_, b2 + i * D_, X, X, BL_, D_, FF_);
    }

    pool_k<<<B_, dim3(512), 0, stream>>>(X, mask, GC);
    gpart_k<<<(B_ * 128) / 4, blk, 0, stream>>>(GC, h1_w, h1_b, GP);
    cast_k<<<(int)((S / 8 + 255) / 256), blk, 0, stream>>>(X, NbB, (int)(S / 8));
    mgemm_k<false,false,false,true><<<MT * 1, blk, 0, stream>>>(
        NbB, h1wB, GP, nullptr, Hb, BL_, 128, D_);
    ln_k<128,true,false><<<lnGrid, blk, 0, stream>>>(Hb, hln_s, hln_b, Hb, BL_);
    logits_k<<<lnGrid, blk, 0, stream>>>(Hb, h2_w, h2_b, out, BL_);
}